// Round 17
// baseline (978.438 us; speedup 1.0000x reference)
//
#include <hip/hip_runtime.h>
#include <hip/hip_bf16.h>
#include <hip/hip_cooperative_groups.h>
#include <cstdint>

namespace cg = cooperative_groups;

#define B_SZ   2048
#define D_INN  1024
#define H_SZ   2048
#define D_OUTN 1024
#define TMAX   12
#define LDW    3072
#define NSL    12       // K-slices for the halt-dot partials (8 h + 4 x)
#define SLC    256

typedef _Float16 f16;
typedef __attribute__((ext_vector_type(8))) _Float16 f16x8;
typedef __attribute__((ext_vector_type(4))) float    f32x4;

typedef const __attribute__((address_space(1))) uint32_t* gptr_t;
typedef __attribute__((address_space(3))) uint32_t*       lptr_t;
__device__ inline void gld16(const void* g, void* l) {   // 16B global->LDS DMA
    __builtin_amdgcn_global_load_lds((gptr_t)g, (lptr_t)l, 16, 0, 0);
}

// ---------------------------------------------------------------------------
// Single-fp16 NT GEMM (halting comes from the exact fp64 linear path).
// r7-verified schedule at BK=64: 64xBN tile, 512 thr / 8 waves (2x4 grid);
// 3 LDS buffers; STAGE(ki+1) -> vmcnt(NV) -> s_barrier (counted, never 0
// in-loop); XOR swizzle c^=(c>>3)&7 (~2-way residual = free); XCD-chunked
// bijective blockIdx swizzle; 2 blocks/CU. Lean epilogue: +Cadd16/+radd,
// Cf (fp32) or Cs (fp16) out.
// ---------------------------------------------------------------------------
template<int BN>
__global__ __launch_bounds__(512, 4) void gemm16(
    const f16* __restrict__ A, int lda,
    const f16* __restrict__ Bm, int ldb,
    const f16*  __restrict__ Cadd16,  // optional [M,ldc] fp16
    const float* __restrict__ radd,   // optional [N]
    float* __restrict__ Cf,           // optional fp32 out
    f16* __restrict__ Cs,             // optional fp16 out
    int ldc, int K, int nx)
{
    constexpr int WN = BN / 64;             // n-frags per wave (2 or 1)
    constexpr int NV = (BN == 128) ? 3 : 2; // vmem loads/thread/STAGE
    __shared__ __align__(16) f16 As[3][64 * 64];
    __shared__ __align__(16) f16 Bs[3][BN * 64];
    const int tid  = threadIdx.x;
    const int wave = tid >> 6;
    const int lane = tid & 63;

    const int nwg = gridDim.x;
    const int cpx = nwg >> 3;
    const int bid = (blockIdx.x & 7) * cpx + (blockIdx.x >> 3);
    const int m0 = (bid / nx) * 64, n0 = (bid % nx) * BN;

    const int wr = wave >> 2, wc = wave & 3;      // 2x4 wave grid
    const int fr = lane & 15, fq = lane >> 4;

    // staging: chunk c (16B) -> LDS slot c (linear); global source chunk
    // swizzled by the involution c ^= ((c>>3)&7)  (row = c>>3, 8 chunks/row)
    const int acs = tid ^ ((tid >> 3) & 7);                    // A: 512 chunks
    const f16* gA = A + (size_t)(m0 + (acs >> 3)) * lda + (acs & 7) * 8;
    const int adst = wave << 9;        // wave-uniform dest base (f16 units)
    const int bcs1 = tid ^ ((tid >> 3) & 7);                   // B chunk tid
    const f16* gB1 = Bm + (size_t)(n0 + (bcs1 >> 3)) * ldb + (bcs1 & 7) * 8;
    const int bdst1 = wave << 9;
    const f16* gB2 = nullptr;
    int bdst2 = 0;
    if constexpr (BN == 128) {                                 // B chunk tid+512
        const int bc2 = tid + 512;
        const int bcs2 = bc2 ^ ((bc2 >> 3) & 7);
        gB2 = Bm + (size_t)(n0 + (bcs2 >> 3)) * ldb + (bcs2 & 7) * 8;
        bdst2 = 4096 + (wave << 9);
    }

    // swizzled fragment read offsets (f16 units), k-invariant
    int offA[2][2], offB[WN][2];
#pragma unroll
    for (int m = 0; m < 2; ++m)
#pragma unroll
        for (int ks = 0; ks < 2; ++ks) {
            const int row = wr * 32 + m * 16 + fr;
            offA[m][ks] = row * 64 + (((ks * 4 + fq) ^ (row & 7)) << 3);
        }
#pragma unroll
    for (int n = 0; n < WN; ++n)
#pragma unroll
        for (int ks = 0; ks < 2; ++ks) {
            const int row = wc * (WN * 16) + n * 16 + fr;
            offB[n][ks] = row * 64 + (((ks * 4 + fq) ^ (row & 7)) << 3);
        }

    auto STAGE = [&](int buf, int ko) {
        gld16(gA + ko,  &As[buf][0] + adst);
        gld16(gB1 + ko, &Bs[buf][0] + bdst1);
        if constexpr (BN == 128) gld16(gB2 + ko, &Bs[buf][0] + bdst2);
    };

    f32x4 acc[2][WN] = {};

    STAGE(0, 0);
    const int nk = K >> 6;
    int cur = 0;
    for (int ki = 0; ki < nk; ++ki) {
        const int nxt = (cur == 2) ? 0 : cur + 1;
        if (ki + 1 < nk) {
            STAGE(nxt, (ki + 1) << 6);
            asm volatile("s_waitcnt vmcnt(%0)" :: "i"(NV) : "memory");
        } else {
            asm volatile("s_waitcnt vmcnt(0)" ::: "memory");
        }
        __builtin_amdgcn_s_barrier();
        asm volatile("" ::: "memory");   // keep ds_reads below the barrier

        f16x8 a[2][2], b[WN][2];
#pragma unroll
        for (int m = 0; m < 2; ++m)
#pragma unroll
            for (int ks = 0; ks < 2; ++ks)
                a[m][ks] = *(const f16x8*)(&As[cur][offA[m][ks]]);
#pragma unroll
        for (int n = 0; n < WN; ++n)
#pragma unroll
            for (int ks = 0; ks < 2; ++ks)
                b[n][ks] = *(const f16x8*)(&Bs[cur][offB[n][ks]]);
#pragma unroll
        for (int ks = 0; ks < 2; ++ks)
#pragma unroll
            for (int m = 0; m < 2; ++m)
#pragma unroll
                for (int n = 0; n < WN; ++n)
                    acc[m][n] = __builtin_amdgcn_mfma_f32_16x16x32_f16(
                        a[m][ks], b[n][ks], acc[m][n], 0, 0, 0);
        cur = nxt;
    }

    // epilogue. C/D layout: col = lane&15, row = (lane>>4)*4 + reg
#pragma unroll
    for (int m = 0; m < 2; ++m) {
#pragma unroll
        for (int n = 0; n < WN; ++n) {
#pragma unroll
            for (int r = 0; r < 4; ++r) {
                const int row = m0 + wr * 32 + m * 16 + fq * 4 + r;
                const int col = n0 + wc * (WN * 16) + n * 16 + fr;
                const size_t o = (size_t)row * ldc + col;
                float v = acc[m][n][r];
                if (Cadd16) v += (float)Cadd16[o];
                if (radd)   v += radd[col];
                if (Cf) Cf[o] = v;
                if (Cs) Cs[o] = (f16)v;
            }
        }
    }
}

// hidden (+)= w_{tbase}[b]*S0[b] + w_{tbase+1}[b]*S1[b] + w_{tbase+2}[b]*S2[b]
// One block per row; f16x8 reads; per-row w==0 skip; fixed accumulation order.
// Last pass (tbase == TMAX-3) also emits the fp16 hidden for the out-GEMM.
__global__ __launch_bounds__(256) void hidacc(
    const f16* __restrict__ s0, const f16* __restrict__ s1,
    const f16* __restrict__ s2, const float* __restrict__ Wmat,
    int tbase, float* __restrict__ hidden, f16* __restrict__ hid16)
{
    const int b = blockIdx.x;
    const float w0 = Wmat[(size_t)(tbase + 0) * B_SZ + b];
    const float w1 = Wmat[(size_t)(tbase + 1) * B_SZ + b];
    const float w2 = Wmat[(size_t)(tbase + 2) * B_SZ + b];
    const bool first = (tbase == 0);
    const bool last  = (tbase == TMAX - 3);
    if (!last && w0 == 0.f && w1 == 0.f && w2 == 0.f) return;

    const int tid = threadIdx.x;
    const size_t o = (size_t)b * H_SZ + tid * 8;
    float hv[8];
    if (first) {
#pragma unroll
        for (int j = 0; j < 8; ++j) hv[j] = 0.f;
    } else {
        const float4 h0 = *(const float4*)(hidden + o);
        const float4 h1 = *(const float4*)(hidden + o + 4);
        hv[0]=h0.x; hv[1]=h0.y; hv[2]=h0.z; hv[3]=h0.w;
        hv[4]=h1.x; hv[5]=h1.y; hv[6]=h1.z; hv[7]=h1.w;
    }
    if (w0 != 0.f) {
        const f16x8 v = *(const f16x8*)(s0 + o);
#pragma unroll
        for (int j = 0; j < 8; ++j) hv[j] += w0 * (float)v[j];
    }
    if (w1 != 0.f) {
        const f16x8 v = *(const f16x8*)(s1 + o);
#pragma unroll
        for (int j = 0; j < 8; ++j) hv[j] += w1 * (float)v[j];
    }
    if (w2 != 0.f) {
        const f16x8 v = *(const f16x8*)(s2 + o);
#pragma unroll
        for (int j = 0; j < 8; ++j) hv[j] += w2 * (float)v[j];
    }
    *(float4*)(hidden + o)     = make_float4(hv[0], hv[1], hv[2], hv[3]);
    *(float4*)(hidden + o + 4) = make_float4(hv[4], hv[5], hv[6], hv[7]);
    if (last) {
        f16x8 hh;
#pragma unroll
        for (int j = 0; j < 8; ++j) hh[j] = (f16)hv[j];
        *(f16x8*)(hid16 + o) = hh;
    }
}

// All five fp32 -> fp16 casts in ONE dispatch (region by blockIdx):
//   [0,1024)    x   [2048x1024] ld 1024 -> xh
//   [1024,3072) h   [2048x2048] ld 2048 -> h16
//   [3072,4096) W_hidden[:, :1024] ld 3072 -> Wxh
//   [4096,6144) W_hidden[:, 1024:] ld 3072 -> Wsh
//   [6144,7168) W_out [1024x2048] ld 2048 -> Woh
__global__ __launch_bounds__(256) void cast_all(
    const float* __restrict__ x, const float* __restrict__ h,
    const float* __restrict__ Wh, const float* __restrict__ Wo,
    f16* __restrict__ xh, f16* __restrict__ h16, f16* __restrict__ Wxh,
    f16* __restrict__ Wsh, f16* __restrict__ Woh)
{
    const int b = blockIdx.x;
    const int tid = threadIdx.x;
    const float* src; f16* dst; int ld, cols, vidx;
    if (b < 1024)      { src = x;          dst = xh;  ld = D_INN; cols = D_INN; vidx = b * 256 + tid; }
    else if (b < 3072) { src = h;          dst = h16; ld = H_SZ;  cols = H_SZ;  vidx = (b - 1024) * 256 + tid; }
    else if (b < 4096) { src = Wh;         dst = Wxh; ld = LDW;   cols = D_INN; vidx = (b - 3072) * 256 + tid; }
    else if (b < 6144) { src = Wh + D_INN; dst = Wsh; ld = LDW;   cols = H_SZ;  vidx = (b - 4096) * 256 + tid; }
    else               { src = Wo;         dst = Woh; ld = H_SZ;  cols = H_SZ;  vidx = (b - 6144) * 256 + tid; }
    const int idx = vidx * 8;
    const int r = idx / cols, c = idx % cols;
    const float* p = src + (size_t)r * ld + c;
    const float4 v0 = *(const float4*)p;
    const float4 v1 = *(const float4*)(p + 4);
    f16x8 o;
    o[0]=(f16)v0.x; o[1]=(f16)v0.y; o[2]=(f16)v0.z; o[3]=(f16)v0.w;
    o[4]=(f16)v1.x; o[5]=(f16)v1.y; o[6]=(f16)v1.z; o[7]=(f16)v1.w;
    *(f16x8*)(dst + idx) = o;
}

// rsum[j] = sum_k W[j,k]  (x+1 correction for the t==0 STATE path), fp32
__global__ __launch_bounds__(256) void rowsum_kernel(
    const float* __restrict__ W, int ld, int K, float* __restrict__ out)
{
    const int j = blockIdx.x;
    const int tid = threadIdx.x;
    float s = 0.f;
    for (int k = tid; k < K; k += 256) s += W[(size_t)j * ld + k];
#pragma unroll
    for (int off = 32; off; off >>= 1) s += __shfl_down(s, off);
    __shared__ float red[4];
    if ((tid & 63) == 0) red[tid >> 6] = s;
    __syncthreads();
    if (tid == 0) out[j] = red[0] + red[1] + red[2] + red[3];
}

// W_hidden [R=2048][C=3072] fp32 -> WT [C][R]  (for coalesced fp64 matvecs)
__global__ __launch_bounds__(256) void transpose_w(
    const float* __restrict__ in, float* __restrict__ out, int R, int C)
{
    __shared__ float t[32][33];
    const int bc = blockIdx.x * 32, br = blockIdx.y * 32;
    const int tx = threadIdx.x & 31, ty = threadIdx.x >> 5;   // 32 x 8
#pragma unroll
    for (int i = 0; i < 32; i += 8)
        t[ty + i][tx] = in[(size_t)(br + ty + i) * C + bc + tx];
    __syncthreads();
#pragma unroll
    for (int i = 0; i < 32; i += 8)
        out[(size_t)(bc + ty + i) * R + br + tx] = t[tx][ty + i];
}

// Cooperative u-chain: U[0] = w_halt; U[k+1][i] = sum_j WT[D_INN+i][j] U[k][j].
// Replaces 12 serial gemv_t dispatches (each ~1us of L2-resident work inside
// ~6us of launch+drain) with ONE dispatch + 12 grid.sync()s. Grid = 256
// blocks (1 per CU -> co-residency guaranteed); each block owns 8 rows.
// Reduction order identical to gemv_t -> bit-identical U.
__global__ __launch_bounds__(256) void u_chain(
    const float* __restrict__ WT, const float* __restrict__ w_halt,
    double* __restrict__ U)
{
    cg::grid_group grid = cg::this_grid();
    const int blk = blockIdx.x;
    const int tid = threadIdx.x;
    for (int i = blk * 256 + tid; i < H_SZ; i += 256 * 256)
        U[i] = (double)w_halt[i];
    grid.sync();
    __shared__ double red[4];
    for (int k = 0; k < TMAX; ++k) {
        const double* uin = U + (size_t)k * H_SZ;
        double* uout = U + (size_t)(k + 1) * H_SZ;
#pragma unroll
        for (int r = 0; r < 8; ++r) {
            const int i = blk * 8 + r;
            const float* row = WT + (size_t)(D_INN + i) * H_SZ;
            double acc = 0.0;
            for (int j = tid; j < H_SZ; j += 256)
                acc += (double)row[j] * uin[j];
#pragma unroll
            for (int off = 32; off; off >>= 1) acc += __shfl_down(acc, off);
            if ((tid & 63) == 0) red[tid >> 6] = acc;
            __syncthreads();
            if (tid == 0) uout[i] = red[0] + red[1] + red[2] + red[3];
            __syncthreads();
        }
        grid.sync();
    }
}

// XU[t][k] = (W_x^T v_t)[k], XS[t][k] = (W_x^T u_t)[k], v_t = sum_{s<=t} u_s
__global__ __launch_bounds__(256) void batch_wx(
    const float* __restrict__ WT, const double* __restrict__ U,
    double* __restrict__ XU, double* __restrict__ XS)
{
    const int k = blockIdx.x;          // 0..D_INN-1
    const int tid = threadIdx.x;
    const float* row = WT + (size_t)k * H_SZ;
    double au[TMAX] = {}, av[TMAX] = {};
    for (int j = tid; j < H_SZ; j += 256) {
        const double w = (double)row[j];
        double pref = 0.0;
#pragma unroll
        for (int t = 0; t < TMAX; ++t) {
            const double u = U[(size_t)t * H_SZ + j];
            pref += u;
            au[t] += w * u;
            av[t] += w * pref;
        }
    }
    __shared__ double red[4][2 * TMAX];
#pragma unroll
    for (int t = 0; t < TMAX; ++t) {
#pragma unroll
        for (int off = 32; off; off >>= 1) {
            au[t] += __shfl_down(au[t], off);
            av[t] += __shfl_down(av[t], off);
        }
    }
    if ((tid & 63) == 0) {
#pragma unroll
        for (int t = 0; t < TMAX; ++t) {
            red[tid >> 6][t] = au[t];
            red[tid >> 6][TMAX + t] = av[t];
        }
    }
    __syncthreads();
    if (tid == 0) {
#pragma unroll
        for (int t = 0; t < TMAX; ++t) {
            XS[(size_t)t * D_INN + k] = red[0][t] + red[1][t] + red[2][t] + red[3][t];
            XU[(size_t)t * D_INN + k] = red[0][TMAX+t] + red[1][TMAX+t]
                                      + red[2][TMAX+t] + red[3][TMAX+t];
        }
    }
}

// E[t] = sum_k XS[t][k] + v_t . b_hidden
__global__ __launch_bounds__(256) void e_kernel(
    const double* __restrict__ XS, const double* __restrict__ U,
    const float* __restrict__ bh, double* __restrict__ E)
{
    const int t = blockIdx.x;
    const int tid = threadIdx.x;
    double a = 0.0;
    for (int k = tid; k < D_INN; k += 256) a += XS[(size_t)t * D_INN + k];
    for (int j = tid; j < H_SZ; j += 256) {
        double v = 0.0;
        for (int s = 0; s <= t; ++s) v += U[(size_t)s * H_SZ + j];
        a += v * (double)bh[j];
    }
#pragma unroll
    for (int off = 32; off; off >>= 1) a += __shfl_down(a, off);
    __shared__ double red[4];
    if ((tid & 63) == 0) red[tid >> 6] = a;
    __syncthreads();
    if (tid == 0) E[t] = red[0] + red[1] + red[2] + red[3];
}

// Halt-dot partials, K-sliced with LDS-cached U.
// Block = 32 rows x one 256-col K-slice; part[b][sl][t] fp64, deterministic.
// Interleaved column map (c = i*32 + lane8*4 + j, float4 loads): conflict-free.
__global__ __launch_bounds__(256) void d_part(
    const float* __restrict__ h, const float* __restrict__ x,
    const double* __restrict__ U, const double* __restrict__ XU,
    double* __restrict__ part)
{
    __shared__ double Us[TMAX][SLC];
    const int blk = blockIdx.x;
    const int sl  = blk % NSL;
    const int br  = (blk / NSL) * 32;
    const int tid = threadIdx.x;
    const int col0 = sl * SLC;
    const bool isH = col0 < H_SZ;
#pragma unroll
    for (int t = 0; t < TMAX; ++t)
        Us[t][tid] = isH ? U[(size_t)(t + 1) * H_SZ + col0 + tid]
                         : XU[(size_t)t * D_INN + (col0 - H_SZ) + tid];
    __syncthreads();
    const int lane8 = tid & 7;
    const int row   = tid >> 3;
    const float* src = isH ? (h + (size_t)(br + row) * H_SZ + col0)
                           : (x + (size_t)(br + row) * D_INN + (col0 - H_SZ));
    double acc[TMAX] = {};
#pragma unroll
    for (int i = 0; i < 8; ++i) {
        const int c = i * 32 + lane8 * 4;
        const float4 v4 = *(const float4*)(src + c);
        const float vv[4] = {v4.x, v4.y, v4.z, v4.w};
#pragma unroll
        for (int j = 0; j < 4; ++j) {
            const double v = (double)vv[j];
#pragma unroll
            for (int t = 0; t < TMAX; ++t) acc[t] += v * Us[t][c + j];
        }
    }
#pragma unroll
    for (int t = 0; t < TMAX; ++t) {
        acc[t] += __shfl_xor(acc[t], 1, 64);
        acc[t] += __shfl_xor(acc[t], 2, 64);
        acc[t] += __shfl_xor(acc[t], 4, 64);
    }
    if (lane8 == 0) {
#pragma unroll
        for (int t = 0; t < TMAX; ++t)
            part[((size_t)(br + row) * NSL + sl) * TMAX + t] = acc[t];
    }
}

// Full ACT halting schedule from the exact dots: w_t[b], ponder[b]
__global__ __launch_bounds__(256) void sched_kernel(
    const double* __restrict__ part, const double* __restrict__ E,
    const float* __restrict__ b_halt,
    float* __restrict__ Wmat, float* __restrict__ ponder)
{
    const int b = blockIdx.x * 256 + threadIdx.x;
    if (b >= B_SZ) return;
    const float bh = b_halt[0];
    float cum = 0.f, R = 0.f;
    int n = -1;
    float w[TMAX];
#pragma unroll
    for (int t = 0; t < TMAX; ++t) {
        double dd = E[t];
#pragma unroll
        for (int sl = 0; sl < NSL; ++sl)
            dd += part[((size_t)b * NSL + sl) * TMAX + t];
        const float p = 1.f / (1.f + expf(-((float)dd + bh)));
        if (n < 0) {
            const float c = cum + p;
            if (c >= 0.99f || t == TMAX - 1) { n = t; R = 1.f - cum; w[t] = R; }
            else { w[t] = p; cum = c; }
        } else {
            w[t] = 0.f;
        }
    }
    ponder[b] = (float)(n + 1) + R;
#pragma unroll
    for (int t = 0; t < TMAX; ++t) Wmat[(size_t)t * B_SZ + b] = w[t];
}

extern "C" void kernel_launch(void* const* d_in, const int* in_sizes, int n_in,
                              void* d_out, int out_size, void* d_ws, size_t ws_size,
                              hipStream_t stream)
{
    const float* x        = (const float*)d_in[0];   // [B, D_IN]
    const float* h        = (const float*)d_in[1];   // [B, H]
    const float* W_hidden = (const float*)d_in[2];   // [H, D_IN+H]
    const float* b_hidden = (const float*)d_in[3];   // [H]
    const float* w_halt   = (const float*)d_in[4];   // [H]
    const float* b_halt   = (const float*)d_in[5];   // [1]
    const float* W_out    = (const float*)d_in[6];   // [D_OUT, H]
    const float* b_out    = (const float*)d_in[7];   // [D_OUT]

    float* out    = (float*)d_out;
    float* output = out;                                   // [B, D_OUT]
    float* hidden = out + (size_t)B_SZ * D_OUTN;           // [B, H]
    float* ponder = hidden + (size_t)B_SZ * H_SZ;          // [B]

    // ---- workspace layout (doubles first for alignment) ----
    double* U    = (double*)d_ws;                          // [13][H]
    double* XU   = U  + (size_t)(TMAX + 1) * H_SZ;         // [12][D_IN]
    double* XS   = XU + (size_t)TMAX * D_INN;              // [12][D_IN]
    double* E    = XS + (size_t)TMAX * D_INN;              // [16]
    double* part = E + 16;                                 // [B][12][12] 2.4MB
    float* rsum  = (float*)(part + (size_t)B_SZ * NSL * TMAX);  // [H]
    float* Wmat  = rsum + H_SZ;                            // [12][B]
    float* WT    = Wmat + (size_t)TMAX * B_SZ;             // [3072][2048] 24MB
    // WT region reuse after the fp64 path is done (all consumers precede):
    f16* xc16  = (f16*)WT;                                 //  0..8MB
    f16* S2    = (f16*)(WT + (size_t)2 * 1024 * 1024);     //  8..16MB
    f16* hid16 = (f16*)(WT + (size_t)4 * 1024 * 1024);     // 16..24MB
    f16* xh   = (f16*)(WT + (size_t)LDW * H_SZ);           // [B][D_IN]  4MB
    f16* Wxh  = xh  + (size_t)B_SZ * D_INN;                // [H][D_IN]  4MB
    f16* S0   = xh;    // ALIAS xh+Wxh (8MB): dead after the xc GEMM
    f16* h16  = Wxh + (size_t)H_SZ * D_INN;                // [B][H]     8MB
    f16* S1   = h16 + (size_t)B_SZ * H_SZ;                 // [B][H]     8MB
    f16* Wsh  = S1  + (size_t)B_SZ * H_SZ;                 // [H][H]     8MB
    f16* Woh  = Wsh + (size_t)H_SZ * H_SZ;                 // [D_OUT][H] 4MB

    const dim3 blk(256);
    const dim3 gblk(512);

    // ---- one-time casts fp32 -> fp16 (single fused dispatch) ----
    cast_all<<<dim3(7168), blk, 0, stream>>>(
        x, h, W_hidden, W_out, xh, h16, Wxh, Wsh, Woh);

    rowsum_kernel<<<dim3(H_SZ), blk, 0, stream>>>(W_hidden, LDW, D_INN, rsum);

    // ---- exact fp64 halting path ----
    transpose_w<<<dim3(LDW / 32, H_SZ / 32), blk, 0, stream>>>(
        W_hidden, WT, H_SZ, LDW);
    {   // cooperative u-chain: one dispatch, 12 grid-syncs
        const float* whp = w_halt;
        const float* wtp = WT;
        double* up = U;
        void* args[] = {(void*)&wtp, (void*)&whp, (void*)&up};
        hipLaunchCooperativeKernel((void*)u_chain, dim3(256), blk, args, 0,
                                   stream);
    }
    batch_wx<<<dim3(D_INN), blk, 0, stream>>>(WT, U, XU, XS);
    e_kernel<<<dim3(TMAX), blk, 0, stream>>>(XS, U, b_hidden, E);
    d_part<<<dim3((B_SZ / 32) * NSL), blk, 0, stream>>>(h, x, U, XU, part);
    sched_kernel<<<dim3(B_SZ / 256), blk, 0, stream>>>(part, E, b_halt,
                                                       Wmat, ponder);

    // ---- state path (single fp16) ----
    // xc16 = fp16(x @ W_x^T + b_hidden)  (into the dead WT region)
    gemm16<128><<<dim3((B_SZ / 64) * (H_SZ / 128)), gblk, 0, stream>>>(
        xh, D_INN, Wxh, D_INN, nullptr, b_hidden, nullptr, xc16,
        H_SZ, D_INN, H_SZ / 128);

    f16* Sb[3] = {S0, S1, S2};
    const f16* prev = h16;
    for (int t = 0; t < TMAX; ++t) {
        f16* curS = Sb[t % 3];
        // s_t = s_{t-1} @ W_s^T + xc16 (+ rsum at t==0), fp16 out only
        gemm16<128><<<dim3((B_SZ / 64) * (H_SZ / 128)), gblk, 0, stream>>>(
            prev, H_SZ, Wsh, H_SZ, xc16, (t == 0) ? rsum : nullptr,
            nullptr, curS, H_SZ, H_SZ, H_SZ / 128);
        prev = curS;
        if ((t % 3) == 2)   // every 3 steps: hidden (+)= w.S  (BW-efficient)
            hidacc<<<dim3(B_SZ), blk, 0, stream>>>(
                S0, S1, S2, Wmat, t - 2, hidden, hid16);
    }

    // output = hidden @ W_out^T + b_out   (sum w = 1 => projection commutes)
    gemm16<64><<<dim3((B_SZ / 64) * (D_OUTN / 64)), gblk, 0, stream>>>(
        hid16, H_SZ, Woh, H_SZ, nullptr, b_out, output, nullptr,
        D_OUTN, H_SZ, D_OUTN / 64);
}

// Round 18
// 542.519 us; speedup vs baseline: 1.8035x; 1.8035x over previous
//
#include <hip/hip_runtime.h>
#include <hip/hip_bf16.h>
#include <cstdint>

#define B_SZ   2048
#define D_INN  1024
#define H_SZ   2048
#define D_OUTN 1024
#define TMAX   12
#define LDW    3072
#define NSL    12       // K-slices for the halt-dot partials (8 h + 4 x)
#define SLC    256

typedef _Float16 f16;
typedef __attribute__((ext_vector_type(8))) _Float16 f16x8;
typedef __attribute__((ext_vector_type(4))) float    f32x4;

typedef const __attribute__((address_space(1))) uint32_t* gptr_t;
typedef __attribute__((address_space(3))) uint32_t*       lptr_t;
__device__ inline void gld16(const void* g, void* l) {   // 16B global->LDS DMA
    __builtin_amdgcn_global_load_lds((gptr_t)g, (lptr_t)l, 16, 0, 0);
}

// ---------------------------------------------------------------------------
// Single-fp16 NT GEMM (halting comes from the exact fp64 linear path).
// r7-verified schedule at BK=64: 64xBN tile, 512 thr / 8 waves (2x4 grid);
// 3 LDS buffers; STAGE(ki+1) -> vmcnt(NV) -> s_barrier (counted, never 0
// in-loop); XOR swizzle c^=(c>>3)&7 (~2-way residual = free); XCD-chunked
// bijective blockIdx swizzle; 2 blocks/CU. Lean epilogue: +Cadd16/+radd,
// Cf (fp32) or Cs (fp16) out.
// ---------------------------------------------------------------------------
template<int BN>
__global__ __launch_bounds__(512, 4) void gemm16(
    const f16* __restrict__ A, int lda,
    const f16* __restrict__ Bm, int ldb,
    const f16*  __restrict__ Cadd16,  // optional [M,ldc] fp16
    const float* __restrict__ radd,   // optional [N]
    float* __restrict__ Cf,           // optional fp32 out
    f16* __restrict__ Cs,             // optional fp16 out
    int ldc, int K, int nx)
{
    constexpr int WN = BN / 64;             // n-frags per wave (2 or 1)
    constexpr int NV = (BN == 128) ? 3 : 2; // vmem loads/thread/STAGE
    __shared__ __align__(16) f16 As[3][64 * 64];
    __shared__ __align__(16) f16 Bs[3][BN * 64];
    const int tid  = threadIdx.x;
    const int wave = tid >> 6;
    const int lane = tid & 63;

    const int nwg = gridDim.x;
    const int cpx = nwg >> 3;
    const int bid = (blockIdx.x & 7) * cpx + (blockIdx.x >> 3);
    const int m0 = (bid / nx) * 64, n0 = (bid % nx) * BN;

    const int wr = wave >> 2, wc = wave & 3;      // 2x4 wave grid
    const int fr = lane & 15, fq = lane >> 4;

    // staging: chunk c (16B) -> LDS slot c (linear); global source chunk
    // swizzled by the involution c ^= ((c>>3)&7)  (row = c>>3, 8 chunks/row)
    const int acs = tid ^ ((tid >> 3) & 7);                    // A: 512 chunks
    const f16* gA = A + (size_t)(m0 + (acs >> 3)) * lda + (acs & 7) * 8;
    const int adst = wave << 9;        // wave-uniform dest base (f16 units)
    const int bcs1 = tid ^ ((tid >> 3) & 7);                   // B chunk tid
    const f16* gB1 = Bm + (size_t)(n0 + (bcs1 >> 3)) * ldb + (bcs1 & 7) * 8;
    const int bdst1 = wave << 9;
    const f16* gB2 = nullptr;
    int bdst2 = 0;
    if constexpr (BN == 128) {                                 // B chunk tid+512
        const int bc2 = tid + 512;
        const int bcs2 = bc2 ^ ((bc2 >> 3) & 7);
        gB2 = Bm + (size_t)(n0 + (bcs2 >> 3)) * ldb + (bcs2 & 7) * 8;
        bdst2 = 4096 + (wave << 9);
    }

    // swizzled fragment read offsets (f16 units), k-invariant
    int offA[2][2], offB[WN][2];
#pragma unroll
    for (int m = 0; m < 2; ++m)
#pragma unroll
        for (int ks = 0; ks < 2; ++ks) {
            const int row = wr * 32 + m * 16 + fr;
            offA[m][ks] = row * 64 + (((ks * 4 + fq) ^ (row & 7)) << 3);
        }
#pragma unroll
    for (int n = 0; n < WN; ++n)
#pragma unroll
        for (int ks = 0; ks < 2; ++ks) {
            const int row = wc * (WN * 16) + n * 16 + fr;
            offB[n][ks] = row * 64 + (((ks * 4 + fq) ^ (row & 7)) << 3);
        }

    auto STAGE = [&](int buf, int ko) {
        gld16(gA + ko,  &As[buf][0] + adst);
        gld16(gB1 + ko, &Bs[buf][0] + bdst1);
        if constexpr (BN == 128) gld16(gB2 + ko, &Bs[buf][0] + bdst2);
    };

    f32x4 acc[2][WN] = {};

    STAGE(0, 0);
    const int nk = K >> 6;
    int cur = 0;
    for (int ki = 0; ki < nk; ++ki) {
        const int nxt = (cur == 2) ? 0 : cur + 1;
        if (ki + 1 < nk) {
            STAGE(nxt, (ki + 1) << 6);
            asm volatile("s_waitcnt vmcnt(%0)" :: "i"(NV) : "memory");
        } else {
            asm volatile("s_waitcnt vmcnt(0)" ::: "memory");
        }
        __builtin_amdgcn_s_barrier();
        asm volatile("" ::: "memory");   // keep ds_reads below the barrier

        f16x8 a[2][2], b[WN][2];
#pragma unroll
        for (int m = 0; m < 2; ++m)
#pragma unroll
            for (int ks = 0; ks < 2; ++ks)
                a[m][ks] = *(const f16x8*)(&As[cur][offA[m][ks]]);
#pragma unroll
        for (int n = 0; n < WN; ++n)
#pragma unroll
            for (int ks = 0; ks < 2; ++ks)
                b[n][ks] = *(const f16x8*)(&Bs[cur][offB[n][ks]]);
#pragma unroll
        for (int ks = 0; ks < 2; ++ks)
#pragma unroll
            for (int m = 0; m < 2; ++m)
#pragma unroll
                for (int n = 0; n < WN; ++n)
                    acc[m][n] = __builtin_amdgcn_mfma_f32_16x16x32_f16(
                        a[m][ks], b[n][ks], acc[m][n], 0, 0, 0);
        cur = nxt;
    }

    // epilogue. C/D layout: col = lane&15, row = (lane>>4)*4 + reg
#pragma unroll
    for (int m = 0; m < 2; ++m) {
#pragma unroll
        for (int n = 0; n < WN; ++n) {
#pragma unroll
            for (int r = 0; r < 4; ++r) {
                const int row = m0 + wr * 32 + m * 16 + fq * 4 + r;
                const int col = n0 + wc * (WN * 16) + n * 16 + fr;
                const size_t o = (size_t)row * ldc + col;
                float v = acc[m][n][r];
                if (Cadd16) v += (float)Cadd16[o];
                if (radd)   v += radd[col];
                if (Cf) Cf[o] = v;
                if (Cs) Cs[o] = (f16)v;
            }
        }
    }
}

// hidden (+)= w_{tbase}[b]*S0[b] + w_{tbase+1}[b]*S1[b] + w_{tbase+2}[b]*S2[b]
// One block per row; f16x8 reads; per-row w==0 skip; fixed accumulation order.
// Last pass (tbase == TMAX-3) also emits the fp16 hidden for the out-GEMM.
__global__ __launch_bounds__(256) void hidacc(
    const f16* __restrict__ s0, const f16* __restrict__ s1,
    const f16* __restrict__ s2, const float* __restrict__ Wmat,
    int tbase, float* __restrict__ hidden, f16* __restrict__ hid16)
{
    const int b = blockIdx.x;
    const float w0 = Wmat[(size_t)(tbase + 0) * B_SZ + b];
    const float w1 = Wmat[(size_t)(tbase + 1) * B_SZ + b];
    const float w2 = Wmat[(size_t)(tbase + 2) * B_SZ + b];
    const bool first = (tbase == 0);
    const bool last  = (tbase == TMAX - 3);
    if (!last && w0 == 0.f && w1 == 0.f && w2 == 0.f) return;

    const int tid = threadIdx.x;
    const size_t o = (size_t)b * H_SZ + tid * 8;
    float hv[8];
    if (first) {
#pragma unroll
        for (int j = 0; j < 8; ++j) hv[j] = 0.f;
    } else {
        const float4 h0 = *(const float4*)(hidden + o);
        const float4 h1 = *(const float4*)(hidden + o + 4);
        hv[0]=h0.x; hv[1]=h0.y; hv[2]=h0.z; hv[3]=h0.w;
        hv[4]=h1.x; hv[5]=h1.y; hv[6]=h1.z; hv[7]=h1.w;
    }
    if (w0 != 0.f) {
        const f16x8 v = *(const f16x8*)(s0 + o);
#pragma unroll
        for (int j = 0; j < 8; ++j) hv[j] += w0 * (float)v[j];
    }
    if (w1 != 0.f) {
        const f16x8 v = *(const f16x8*)(s1 + o);
#pragma unroll
        for (int j = 0; j < 8; ++j) hv[j] += w1 * (float)v[j];
    }
    if (w2 != 0.f) {
        const f16x8 v = *(const f16x8*)(s2 + o);
#pragma unroll
        for (int j = 0; j < 8; ++j) hv[j] += w2 * (float)v[j];
    }
    *(float4*)(hidden + o)     = make_float4(hv[0], hv[1], hv[2], hv[3]);
    *(float4*)(hidden + o + 4) = make_float4(hv[4], hv[5], hv[6], hv[7]);
    if (last) {
        f16x8 hh;
#pragma unroll
        for (int j = 0; j < 8; ++j) hh[j] = (f16)hv[j];
        *(f16x8*)(hid16 + o) = hh;
    }
}

// All five fp32 -> fp16 casts in ONE dispatch (region by blockIdx)
__global__ __launch_bounds__(256) void cast_all(
    const float* __restrict__ x, const float* __restrict__ h,
    const float* __restrict__ Wh, const float* __restrict__ Wo,
    f16* __restrict__ xh, f16* __restrict__ h16, f16* __restrict__ Wxh,
    f16* __restrict__ Wsh, f16* __restrict__ Woh)
{
    const int b = blockIdx.x;
    const int tid = threadIdx.x;
    const float* src; f16* dst; int ld, cols, vidx;
    if (b < 1024)      { src = x;          dst = xh;  ld = D_INN; cols = D_INN; vidx = b * 256 + tid; }
    else if (b < 3072) { src = h;          dst = h16; ld = H_SZ;  cols = H_SZ;  vidx = (b - 1024) * 256 + tid; }
    else if (b < 4096) { src = Wh;         dst = Wxh; ld = LDW;   cols = D_INN; vidx = (b - 3072) * 256 + tid; }
    else if (b < 6144) { src = Wh + D_INN; dst = Wsh; ld = LDW;   cols = H_SZ;  vidx = (b - 4096) * 256 + tid; }
    else               { src = Wo;         dst = Woh; ld = H_SZ;  cols = H_SZ;  vidx = (b - 6144) * 256 + tid; }
    const int idx = vidx * 8;
    const int r = idx / cols, c = idx % cols;
    const float* p = src + (size_t)r * ld + c;
    const float4 v0 = *(const float4*)p;
    const float4 v1 = *(const float4*)(p + 4);
    f16x8 o;
    o[0]=(f16)v0.x; o[1]=(f16)v0.y; o[2]=(f16)v0.z; o[3]=(f16)v0.w;
    o[4]=(f16)v1.x; o[5]=(f16)v1.y; o[6]=(f16)v1.z; o[7]=(f16)v1.w;
    *(f16x8*)(dst + idx) = o;
}

// rsum[j] = sum_k W[j,k]  (x+1 correction for the t==0 STATE path), fp32
__global__ __launch_bounds__(256) void rowsum_kernel(
    const float* __restrict__ W, int ld, int K, float* __restrict__ out)
{
    const int j = blockIdx.x;
    const int tid = threadIdx.x;
    float s = 0.f;
    for (int k = tid; k < K; k += 256) s += W[(size_t)j * ld + k];
#pragma unroll
    for (int off = 32; off; off >>= 1) s += __shfl_down(s, off);
    __shared__ float red[4];
    if ((tid & 63) == 0) red[tid >> 6] = s;
    __syncthreads();
    if (tid == 0) out[j] = red[0] + red[1] + red[2] + red[3];
}

// W_hidden [R=2048][C=3072] fp32 -> WT [C][R]  (for coalesced fp64 matvecs)
__global__ __launch_bounds__(256) void transpose_w(
    const float* __restrict__ in, float* __restrict__ out, int R, int C)
{
    __shared__ float t[32][33];
    const int bc = blockIdx.x * 32, br = blockIdx.y * 32;
    const int tx = threadIdx.x & 31, ty = threadIdx.x >> 5;   // 32 x 8
#pragma unroll
    for (int i = 0; i < 32; i += 8)
        t[ty + i][tx] = in[(size_t)(br + ty + i) * C + bc + tx];
    __syncthreads();
#pragma unroll
    for (int i = 0; i < 32; i += 8)
        out[(size_t)(bc + ty + i) * R + br + tx] = t[tx][ty + i];
}

__global__ __launch_bounds__(256) void init_u0(
    const float* __restrict__ w, double* __restrict__ u)
{
    const int i = blockIdx.x * 256 + threadIdx.x;
    if (i < H_SZ) u[i] = (double)w[i];
}

// u_out[i] = sum_j W_s[j,i] u_in[j] = sum_j WT[D_INN+i][j] u_in[j]  (fp64)
// NOTE (r17 lesson): cooperative grid.sync costs ~40us on MI355X — the
// 12 serial launches (~6us each) are the FASTER implementation.
__global__ __launch_bounds__(256) void gemv_t(
    const float* __restrict__ WT, const double* __restrict__ uin,
    double* __restrict__ uout)
{
    const int i = blockIdx.x;
    const int tid = threadIdx.x;
    const float* row = WT + (size_t)(D_INN + i) * H_SZ;
    double acc = 0.0;
    for (int j = tid; j < H_SZ; j += 256) acc += (double)row[j] * uin[j];
#pragma unroll
    for (int off = 32; off; off >>= 1) acc += __shfl_down(acc, off);
    __shared__ double red[4];
    if ((tid & 63) == 0) red[tid >> 6] = acc;
    __syncthreads();
    if (tid == 0) uout[i] = red[0] + red[1] + red[2] + red[3];
}

// XU[t][k] = (W_x^T v_t)[k], XS[t][k] = (W_x^T u_t)[k], v_t = sum_{s<=t} u_s
__global__ __launch_bounds__(256) void batch_wx(
    const float* __restrict__ WT, const double* __restrict__ U,
    double* __restrict__ XU, double* __restrict__ XS)
{
    const int k = blockIdx.x;          // 0..D_INN-1
    const int tid = threadIdx.x;
    const float* row = WT + (size_t)k * H_SZ;
    double au[TMAX] = {}, av[TMAX] = {};
    for (int j = tid; j < H_SZ; j += 256) {
        const double w = (double)row[j];
        double pref = 0.0;
#pragma unroll
        for (int t = 0; t < TMAX; ++t) {
            const double u = U[(size_t)t * H_SZ + j];
            pref += u;
            au[t] += w * u;
            av[t] += w * pref;
        }
    }
    __shared__ double red[4][2 * TMAX];
#pragma unroll
    for (int t = 0; t < TMAX; ++t) {
#pragma unroll
        for (int off = 32; off; off >>= 1) {
            au[t] += __shfl_down(au[t], off);
            av[t] += __shfl_down(av[t], off);
        }
    }
    if ((tid & 63) == 0) {
#pragma unroll
        for (int t = 0; t < TMAX; ++t) {
            red[tid >> 6][t] = au[t];
            red[tid >> 6][TMAX + t] = av[t];
        }
    }
    __syncthreads();
    if (tid == 0) {
#pragma unroll
        for (int t = 0; t < TMAX; ++t) {
            XS[(size_t)t * D_INN + k] = red[0][t] + red[1][t] + red[2][t] + red[3][t];
            XU[(size_t)t * D_INN + k] = red[0][TMAX+t] + red[1][TMAX+t]
                                      + red[2][TMAX+t] + red[3][TMAX+t];
        }
    }
}

// E[t] = sum_k XS[t][k] + v_t . b_hidden
__global__ __launch_bounds__(256) void e_kernel(
    const double* __restrict__ XS, const double* __restrict__ U,
    const float* __restrict__ bh, double* __restrict__ E)
{
    const int t = blockIdx.x;
    const int tid = threadIdx.x;
    double a = 0.0;
    for (int k = tid; k < D_INN; k += 256) a += XS[(size_t)t * D_INN + k];
    for (int j = tid; j < H_SZ; j += 256) {
        double v = 0.0;
        for (int s = 0; s <= t; ++s) v += U[(size_t)s * H_SZ + j];
        a += v * (double)bh[j];
    }
#pragma unroll
    for (int off = 32; off; off >>= 1) a += __shfl_down(a, off);
    __shared__ double red[4];
    if ((tid & 63) == 0) red[tid >> 6] = a;
    __syncthreads();
    if (tid == 0) E[t] = red[0] + red[1] + red[2] + red[3];
}

// Halt-dot partials, K-sliced with LDS-cached U.
// Block = 32 rows x one 256-col K-slice; part[b][sl][t] fp64, deterministic.
// Interleaved column map (c = i*32 + lane8*4 + j, float4 loads): conflict-free.
__global__ __launch_bounds__(256) void d_part(
    const float* __restrict__ h, const float* __restrict__ x,
    const double* __restrict__ U, const double* __restrict__ XU,
    double* __restrict__ part)
{
    __shared__ double Us[TMAX][SLC];
    const int blk = blockIdx.x;
    const int sl  = blk % NSL;
    const int br  = (blk / NSL) * 32;
    const int tid = threadIdx.x;
    const int col0 = sl * SLC;
    const bool isH = col0 < H_SZ;
#pragma unroll
    for (int t = 0; t < TMAX; ++t)
        Us[t][tid] = isH ? U[(size_t)(t + 1) * H_SZ + col0 + tid]
                         : XU[(size_t)t * D_INN + (col0 - H_SZ) + tid];
    __syncthreads();
    const int lane8 = tid & 7;
    const int row   = tid >> 3;
    const float* src = isH ? (h + (size_t)(br + row) * H_SZ + col0)
                           : (x + (size_t)(br + row) * D_INN + (col0 - H_SZ));
    double acc[TMAX] = {};
#pragma unroll
    for (int i = 0; i < 8; ++i) {
        const int c = i * 32 + lane8 * 4;
        const float4 v4 = *(const float4*)(src + c);
        const float vv[4] = {v4.x, v4.y, v4.z, v4.w};
#pragma unroll
        for (int j = 0; j < 4; ++j) {
            const double v = (double)vv[j];
#pragma unroll
            for (int t = 0; t < TMAX; ++t) acc[t] += v * Us[t][c + j];
        }
    }
#pragma unroll
    for (int t = 0; t < TMAX; ++t) {
        acc[t] += __shfl_xor(acc[t], 1, 64);
        acc[t] += __shfl_xor(acc[t], 2, 64);
        acc[t] += __shfl_xor(acc[t], 4, 64);
    }
    if (lane8 == 0) {
#pragma unroll
        for (int t = 0; t < TMAX; ++t)
            part[((size_t)(br + row) * NSL + sl) * TMAX + t] = acc[t];
    }
}

// Full ACT halting schedule from the exact dots: w_t[b], ponder[b]
__global__ __launch_bounds__(256) void sched_kernel(
    const double* __restrict__ part, const double* __restrict__ E,
    const float* __restrict__ b_halt,
    float* __restrict__ Wmat, float* __restrict__ ponder)
{
    const int b = blockIdx.x * 256 + threadIdx.x;
    if (b >= B_SZ) return;
    const float bh = b_halt[0];
    float cum = 0.f, R = 0.f;
    int n = -1;
    float w[TMAX];
#pragma unroll
    for (int t = 0; t < TMAX; ++t) {
        double dd = E[t];
#pragma unroll
        for (int sl = 0; sl < NSL; ++sl)
            dd += part[((size_t)b * NSL + sl) * TMAX + t];
        const float p = 1.f / (1.f + expf(-((float)dd + bh)));
        if (n < 0) {
            const float c = cum + p;
            if (c >= 0.99f || t == TMAX - 1) { n = t; R = 1.f - cum; w[t] = R; }
            else { w[t] = p; cum = c; }
        } else {
            w[t] = 0.f;
        }
    }
    ponder[b] = (float)(n + 1) + R;
#pragma unroll
    for (int t = 0; t < TMAX; ++t) Wmat[(size_t)t * B_SZ + b] = w[t];
}

extern "C" void kernel_launch(void* const* d_in, const int* in_sizes, int n_in,
                              void* d_out, int out_size, void* d_ws, size_t ws_size,
                              hipStream_t stream)
{
    const float* x        = (const float*)d_in[0];   // [B, D_IN]
    const float* h        = (const float*)d_in[1];   // [B, H]
    const float* W_hidden = (const float*)d_in[2];   // [H, D_IN+H]
    const float* b_hidden = (const float*)d_in[3];   // [H]
    const float* w_halt   = (const float*)d_in[4];   // [H]
    const float* b_halt   = (const float*)d_in[5];   // [1]
    const float* W_out    = (const float*)d_in[6];   // [D_OUT, H]
    const float* b_out    = (const float*)d_in[7];   // [D_OUT]

    float* out    = (float*)d_out;
    float* output = out;                                   // [B, D_OUT]
    float* hidden = out + (size_t)B_SZ * D_OUTN;           // [B, H]
    float* ponder = hidden + (size_t)B_SZ * H_SZ;          // [B]

    // ---- workspace layout (doubles first for alignment) ----
    double* U    = (double*)d_ws;                          // [13][H]
    double* XU   = U  + (size_t)(TMAX + 1) * H_SZ;         // [12][D_IN]
    double* XS   = XU + (size_t)TMAX * D_INN;              // [12][D_IN]
    double* E    = XS + (size_t)TMAX * D_INN;              // [16]
    double* part = E + 16;                                 // [B][12][12] 2.4MB
    float* rsum  = (float*)(part + (size_t)B_SZ * NSL * TMAX);  // [H]
    float* Wmat  = rsum + H_SZ;                            // [12][B]
    float* WT    = Wmat + (size_t)TMAX * B_SZ;             // [3072][2048] 24MB
    // WT region reuse after the fp64 path is done (all consumers precede):
    f16* xc16  = (f16*)WT;                                 //  0..8MB
    f16* S2    = (f16*)(WT + (size_t)2 * 1024 * 1024);     //  8..16MB
    f16* hid16 = (f16*)(WT + (size_t)4 * 1024 * 1024);     // 16..24MB
    f16* xh   = (f16*)(WT + (size_t)LDW * H_SZ);           // [B][D_IN]  4MB
    f16* Wxh  = xh  + (size_t)B_SZ * D_INN;                // [H][D_IN]  4MB
    f16* S0   = xh;    // ALIAS xh+Wxh (8MB): dead after the xc GEMM
    f16* h16  = Wxh + (size_t)H_SZ * D_INN;                // [B][H]     8MB
    f16* S1   = h16 + (size_t)B_SZ * H_SZ;                 // [B][H]     8MB
    f16* Wsh  = S1  + (size_t)B_SZ * H_SZ;                 // [H][H]     8MB
    f16* Woh  = Wsh + (size_t)H_SZ * H_SZ;                 // [D_OUT][H] 4MB

    const dim3 blk(256);
    const dim3 gblk(512);

    // ---- one-time casts fp32 -> fp16 (single fused dispatch) ----
    cast_all<<<dim3(7168), blk, 0, stream>>>(
        x, h, W_hidden, W_out, xh, h16, Wxh, Wsh, Woh);

    rowsum_kernel<<<dim3(H_SZ), blk, 0, stream>>>(W_hidden, LDW, D_INN, rsum);

    // ---- exact fp64 halting path ----
    transpose_w<<<dim3(LDW / 32, H_SZ / 32), blk, 0, stream>>>(
        W_hidden, WT, H_SZ, LDW);
    init_u0<<<dim3(H_SZ / 256), blk, 0, stream>>>(w_halt, U);
    for (int k = 0; k < TMAX; ++k)
        gemv_t<<<dim3(H_SZ), blk, 0, stream>>>(WT, U + (size_t)k * H_SZ,
                                               U + (size_t)(k + 1) * H_SZ);
    batch_wx<<<dim3(D_INN), blk, 0, stream>>>(WT, U, XU, XS);
    e_kernel<<<dim3(TMAX), blk, 0, stream>>>(XS, U, b_hidden, E);
    d_part<<<dim3((B_SZ / 32) * NSL), blk, 0, stream>>>(h, x, U, XU, part);
    sched_kernel<<<dim3(B_SZ / 256), blk, 0, stream>>>(part, E, b_halt,
                                                       Wmat, ponder);

    // ---- state path (single fp16) ----
    // xc16 = fp16(x @ W_x^T + b_hidden)  (into the dead WT region)
    gemm16<128><<<dim3((B_SZ / 64) * (H_SZ / 128)), gblk, 0, stream>>>(
        xh, D_INN, Wxh, D_INN, nullptr, b_hidden, nullptr, xc16,
        H_SZ, D_INN, H_SZ / 128);

    f16* Sb[3] = {S0, S1, S2};
    const f16* prev = h16;
    for (int t = 0; t < TMAX; ++t) {
        f16* curS = Sb[t % 3];
        // s_t = s_{t-1} @ W_s^T + xc16 (+ rsum at t==0), fp16 out only
        gemm16<128><<<dim3((B_SZ / 64) * (H_SZ / 128)), gblk, 0, stream>>>(
            prev, H_SZ, Wsh, H_SZ, xc16, (t == 0) ? rsum : nullptr,
            nullptr, curS, H_SZ, H_SZ, H_SZ / 128);
        prev = curS;
        if ((t % 3) == 2)   // every 3 steps: hidden (+)= w.S  (BW-efficient)
            hidacc<<<dim3(B_SZ), blk, 0, stream>>>(
                S0, S1, S2, Wmat, t - 2, hidden, hid16);
    }

    // output = hidden @ W_out^T + b_out   (sum w = 1 => projection commutes)
    gemm16<64><<<dim3((B_SZ / 64) * (D_OUTN / 64)), gblk, 0, stream>>>(
        hid16, H_SZ, Woh, H_SZ, nullptr, b_out, output, nullptr,
        D_OUTN, H_SZ, D_OUTN / 64);
}